// Round 2
// baseline (107.432 us; speedup 1.0000x reference)
//
#include <hip/hip_runtime.h>
#include <hip/hip_bf16.h>
#include <stdint.h>

#define LOG2E 1.4426950408889634f

typedef float f32x4 __attribute__((ext_vector_type(4)));
typedef short s16x8 __attribute__((ext_vector_type(8)));
typedef int   i32x4 __attribute__((ext_vector_type(4)));

__device__ __forceinline__ float bf2f(uint16_t u) {
    uint32_t x = ((uint32_t)u) << 16;
    float f;
    __builtin_memcpy(&f, &x, 4);
    return f;
}
__device__ __forceinline__ uint16_t f2bf(float f) {
    uint32_t x;
    __builtin_memcpy(&x, &f, 4);
    uint32_t r = (x + 0x7fffu + ((x >> 16) & 1u)) >> 16;
    return (uint16_t)r;
}

// -------------------- Kernel 0: split W (fp32) into hi/lo bf16 --------------------
__global__ __launch_bounds__(256) void k0_splitW(
    const float* __restrict__ W, uint16_t* __restrict__ whi, uint16_t* __restrict__ wlo)
{
    int i = blockIdx.x * 256 + threadIdx.x;
    float x = W[i];
    uint16_t hb = f2bf(x);
    whi[i] = hb;
    wlo[i] = f2bf(x - bf2f(hb));
}

// -------------------- Kernel 1: Wh via split-bf16 MFMA; whB frag-order; s1/E1/E2; rowgroup max --
__global__ __launch_bounds__(256) void k1_gemm(
    const float* __restrict__ h, const uint16_t* __restrict__ whi_,
    const uint16_t* __restrict__ wlo_,
    const float* __restrict__ aw, const float* __restrict__ ab,
    uint16_t* __restrict__ whB, float* __restrict__ s1b,
    float* __restrict__ E1g, float* __restrict__ E2g,
    float* __restrict__ smaxrg)
{
    __shared__ float sred[4][16][2];
    const int tid = threadIdx.x;
    const int w = tid >> 6, lane = tid & 63;
    const int q = lane >> 4, n16 = lane & 15;
    const int R0 = blockIdx.x * 16;
    const int f0 = w * 32;

    f32x4 acc[2];
    acc[0] = 0.f; acc[1] = 0.f;

    const float* hrow = h + (size_t)(R0 + n16) * 128 + q * 8;
    const uint16_t* whbase = whi_ + (size_t)(f0 + n16) * 128 + q * 8;
    const uint16_t* wlbase = wlo_ + (size_t)(f0 + n16) * 128 + q * 8;
#pragma unroll
    for (int kc = 0; kc < 4; ++kc) {
        float4 x0 = *(const float4*)(hrow + kc * 32);
        float4 x1 = *(const float4*)(hrow + kc * 32 + 4);
        float xs[8] = {x0.x, x0.y, x0.z, x0.w, x1.x, x1.y, x1.z, x1.w};
        s16x8 ahi, alo;
#pragma unroll
        for (int t = 0; t < 8; ++t) {
            uint16_t hb = f2bf(xs[t]);
            ahi[t] = (short)hb;
            alo[t] = (short)f2bf(xs[t] - bf2f(hb));
        }
#pragma unroll
        for (int fb = 0; fb < 2; ++fb) {
            s16x8 bhi = *(const s16x8*)(whbase + fb * 16 * 128 + kc * 32);
            s16x8 blo = *(const s16x8*)(wlbase + fb * 16 * 128 + kc * 32);
            acc[fb] = __builtin_amdgcn_mfma_f32_16x16x32_bf16(ahi, bhi, acc[fb], 0, 0, 0);
            acc[fb] = __builtin_amdgcn_mfma_f32_16x16x32_bf16(alo, bhi, acc[fb], 0, 0, 0);
            acc[fb] = __builtin_amdgcn_mfma_f32_16x16x32_bf16(ahi, blo, acc[fb], 0, 0, 0);
        }
    }

    float s1p[4] = {0.f, 0.f, 0.f, 0.f}, s2p[4] = {0.f, 0.f, 0.f, 0.f};
#pragma unroll
    for (int fb = 0; fb < 2; ++fb) {
        float a1 = aw[f0 + fb * 16 + n16];
        float a2 = aw[128 + f0 + fb * 16 + n16];
#pragma unroll
        for (int reg = 0; reg < 4; ++reg) {
            s1p[reg] = fmaf(acc[fb][reg], a1, s1p[reg]);
            s2p[reg] = fmaf(acc[fb][reg], a2, s2p[reg]);
        }
    }
#pragma unroll
    for (int off = 1; off < 16; off <<= 1) {
#pragma unroll
        for (int reg = 0; reg < 4; ++reg) {
            s1p[reg] += __shfl_xor(s1p[reg], off);
            s2p[reg] += __shfl_xor(s2p[reg], off);
        }
    }
    if (n16 == 0) {
#pragma unroll
        for (int reg = 0; reg < 4; ++reg) {
            sred[w][q * 4 + reg][0] = s1p[reg];
            sred[w][q * 4 + reg][1] = s2p[reg];
        }
    }
    __syncthreads();
    if (tid < 16) {
        float s1 = sred[0][tid][0] + sred[1][tid][0] + sred[2][tid][0] + sred[3][tid][0];
        float s2 = sred[0][tid][1] + sred[1][tid][1] + sred[2][tid][1] + sred[3][tid][1];
        int R = R0 + tid;
        s1b[R] = LOG2E * (s1 + ab[0]);
        float s2s = LOG2E * s2;
        E1g[R] = __builtin_amdgcn_exp2f(s2s);
        E2g[R] = __builtin_amdgcn_exp2f(0.2f * s2s);
        float m = s2s;
#pragma unroll
        for (int off = 1; off < 16; off <<= 1)
            m = fmaxf(m, __shfl_xor(m, off));
        if (tid == 0) smaxrg[blockIdx.x] = m;
    }

    const int b = R0 >> 10;
    const int jt = (R0 & 1023) >> 5;
    const int rg1 = (R0 >> 4) & 1;
    uint16_t* base = whB + (size_t)b * 131072 + (size_t)jt * 512;
    const int lane8p = (rg1 * 2 + (q >> 1)) * 16 + n16;
#pragma unroll
    for (int fb = 0; fb < 2; ++fb) {
        int fblk = w * 2 + fb;
        uint32_t e0 = f2bf(acc[fb][0]), e1 = f2bf(acc[fb][1]);
        uint32_t e2 = f2bf(acc[fb][2]), e3 = f2bf(acc[fb][3]);
        uint2 val = make_uint2(e0 | (e1 << 16), e2 | (e3 << 16));
        *(uint2*)(base + fblk * 16384 + lane8p * 8 + (q & 1) * 4) = val;
    }
}

// -------------------- Kernel 2: fused attention v5 ---------------------------------------------
// 2048 blocks x 2 waves (128 threads). Block = 32 rows x 32 f; the two waves SPLIT the j-sweep
// (wave w: jt in [16w, 16w+16)) -> 4096 waves = 4 waves/SIMD (2x occupancy vs v4) to cover the
// L2 load latency the 1-tile prefetch can't hide at 2 waves/SIMD.
// Since M is a precomputed global batch max there is no online rescaling: partials combine by
// plain fp32 addition (6 KB LDS exchange). Epilogue also splits: wave w owns rowfrag rf=w.
// P-path numerics (exp2/mul/max/truncate) are bit-identical to v4.
__global__ __launch_bounds__(128, 4) void k2_attn(
    const uint16_t* __restrict__ whB, const float* __restrict__ s1b,
    const float* __restrict__ E1g, const float* __restrict__ E2g,
    const float* __restrict__ smaxrg, float* __restrict__ out)
{
    __shared__ float red[2][12][64];
    const int tid = threadIdx.x;
    const int wv = tid >> 6;             // wave id: j-half AND epilogue rowfrag
    const int lane = tid & 63;
    const int q = lane >> 4, n16 = lane & 15;
    const int idx = blockIdx.x;
    const int xcd = idx & 7;
    const int o = idx >> 3;              // [0,256)
    const int b = ((o >> 7) << 3) | xcd; // batches {xcd, xcd+8} stay on one XCD's L2
    const int rem = o & 127;
    const int rg = rem >> 2;             // rowgroup of 32 rows
    const int fq = rem & 3;              // f-quarter (32 f)
    const int jb = b << 10;
    const int iw0 = rg * 32;
    const int f0 = fq * 32;

    // batch max of s2 (plain max; softmax shift-invariance keeps ratio exact)
    float M = smaxrg[(b << 6) | lane];
#pragma unroll
    for (int off = 1; off < 64; off <<= 1)
        M = fmaxf(M, __shfl_xor(M, off));

    // per-lane A-row constants for rowfrags rf=0,1 (rows iw0 + rf*16 + n16), hoisted exps
    float eA[2], eB[2];
#pragma unroll
    for (int rf = 0; rf < 2; ++rf) {
        float s1v = s1b[jb + iw0 + rf * 16 + n16];
        float tm = s1v + M;
        float mi = fmaxf(tm, 0.2f * tm);
        eA[rf] = __builtin_amdgcn_exp2f(s1v - mi);
        eB[rf] = __builtin_amdgcn_exp2f(fmaf(0.2f, s1v, -mi));
    }

    f32x4 acc[2][2], accl[2];
#pragma unroll
    for (int rf = 0; rf < 2; ++rf) {
        acc[rf][0] = 0.f; acc[rf][1] = 0.f; accl[rf] = 0.f;
    }

    s16x8 Bones;
#pragma unroll
    for (int t = 0; t < 8; ++t) Bones[t] = (short)0x3F80;  // bf16(1.0)

    const int fblk0 = fq * 2, fblk1 = fq * 2 + 1;
    const int jt0 = wv << 4;
    const uint16_t* wb = whB + ((size_t)b << 17) + lane * 8;
    const uint16_t* wb0 = wb + jt0 * 512;
    const float* e1q = E1g + jb + jt0 * 32 + q * 8;
    const float* e2q = E2g + jb + jt0 * 32 + q * 8;

    s16x8 Bc0 = *(const s16x8*)(wb0 + fblk0 * 16384);
    s16x8 Bc1 = *(const s16x8*)(wb0 + fblk1 * 16384);
    float4 c1a = *(const float4*)(e1q);
    float4 c1b = *(const float4*)(e1q + 4);
    float4 c2a = *(const float4*)(e2q);
    float4 c2b = *(const float4*)(e2q + 4);

    for (int t = 0; t < 16; ++t) {
        const int tn = (t < 15) ? t + 1 : 15;
        const uint16_t* bpn = wb0 + tn * 512;
        s16x8 Bn0 = *(const s16x8*)(bpn + fblk0 * 16384);
        s16x8 Bn1 = *(const s16x8*)(bpn + fblk1 * 16384);
        float4 n1a = *(const float4*)(e1q + tn * 32);
        float4 n1b = *(const float4*)(e1q + tn * 32 + 4);
        float4 n2a = *(const float4*)(e2q + tn * 32);
        float4 n2b = *(const float4*)(e2q + tn * 32 + 4);

        float e1v[8] = {c1a.x, c1a.y, c1a.z, c1a.w, c1b.x, c1b.y, c1b.z, c1b.w};
        float e2v[8] = {c2a.x, c2a.y, c2a.z, c2a.w, c2b.x, c2b.y, c2b.z, c2b.w};

        s16x8 A[2];
#pragma unroll
        for (int rf = 0; rf < 2; ++rf) {
            i32x4 pk;
#pragma unroll
            for (int pr = 0; pr < 4; ++pr) {
                float p0 = fmaxf(eA[rf] * e1v[2 * pr],     eB[rf] * e2v[2 * pr]);
                float p1 = fmaxf(eA[rf] * e1v[2 * pr + 1], eB[rf] * e2v[2 * pr + 1]);
                // dst = { p1[31:16], p0[31:16] } : truncation pack in one v_perm_b32
                pk[pr] = (int)__builtin_amdgcn_perm(
                    __builtin_bit_cast(uint32_t, p1),
                    __builtin_bit_cast(uint32_t, p0), 0x07060302u);
            }
            A[rf] = __builtin_bit_cast(s16x8, pk);
        }
#pragma unroll
        for (int rf = 0; rf < 2; ++rf) {
            acc[rf][0] = __builtin_amdgcn_mfma_f32_16x16x32_bf16(A[rf], Bc0, acc[rf][0], 0, 0, 0);
            acc[rf][1] = __builtin_amdgcn_mfma_f32_16x16x32_bf16(A[rf], Bc1, acc[rf][1], 0, 0, 0);
            accl[rf]   = __builtin_amdgcn_mfma_f32_16x16x32_bf16(A[rf], Bones, accl[rf], 0, 0, 0);
        }
        Bc0 = Bn0; Bc1 = Bn1;
        c1a = n1a; c1b = n1b; c2a = n2a; c2b = n2b;
    }

    // cross-wave combine: wave wv exports its partials for rowfrag (1-wv), imports its own.
    const int orf = 1 - wv;
#pragma unroll
    for (int fb = 0; fb < 2; ++fb)
#pragma unroll
        for (int reg = 0; reg < 4; ++reg)
            red[wv][fb * 4 + reg][lane] = acc[orf][fb][reg];
#pragma unroll
    for (int reg = 0; reg < 4; ++reg)
        red[wv][8 + reg][lane] = accl[orf][reg];
    __syncthreads();
#pragma unroll
    for (int fb = 0; fb < 2; ++fb)
#pragma unroll
        for (int reg = 0; reg < 4; ++reg)
            acc[wv][fb][reg] += red[orf][fb * 4 + reg][lane];
#pragma unroll
    for (int reg = 0; reg < 4; ++reg)
        accl[wv][reg] += red[orf][8 + reg][lane];

    // post-loop diagonal subtraction for THIS wave's rowfrag rf=wv.
    // Same product/max/truncate sequence as the main loop -> bit-exact cancellation.
    {
        const int rf = wv;
#pragma unroll
        for (int reg = 0; reg < 4; ++reg) {
            int iw = iw0 + rf * 16 + q * 4 + reg;
            float s1v = s1b[jb + iw];
            float tm = s1v + M;
            float mi = fmaxf(tm, 0.2f * tm);
            float eAr = __builtin_amdgcn_exp2f(s1v - mi);
            float eBr = __builtin_amdgcn_exp2f(fmaf(0.2f, s1v, -mi));
            float p = fmaxf(eAr * E1g[jb + iw], eBr * E2g[jb + iw]);
            float pt = __builtin_bit_cast(float, __builtin_bit_cast(uint32_t, p) & 0xffff0000u);
            accl[rf][reg] -= pt;
            int lane_i = ((iw >> 3) & 3) * 16 + n16;
#pragma unroll
            for (int fb = 0; fb < 2; ++fb) {
                size_t a = ((size_t)b << 17) + (size_t)(fq * 2 + fb) * 16384 +
                           (size_t)(iw >> 5) * 512 + lane_i * 8 + (iw & 7);
                float wv_ = bf2f(whB[a]);
                acc[rf][fb][reg] -= pt * wv_;
            }
        }
    }

    // epilogue for rf=wv: scale by 1/l (in-layout, no shuffles), elu, store fp32
    {
        const int rf = wv;
#pragma unroll
        for (int reg = 0; reg < 4; ++reg) {
            float rl = 1.0f / accl[rf][reg];
            int row = jb + iw0 + rf * 16 + q * 4 + reg;
#pragma unroll
            for (int fb = 0; fb < 2; ++fb) {
                float v = acc[rf][fb][reg] * rl;
                float e = v > 0.f ? v : (__builtin_amdgcn_exp2f(v * LOG2E) - 1.f);
                out[(size_t)row * 128 + f0 + fb * 16 + n16] = e;
            }
        }
    }
}

extern "C" void kernel_launch(void* const* d_in, const int* in_sizes, int n_in,
                              void* d_out, int out_size, void* d_ws, size_t ws_size,
                              hipStream_t stream) {
    (void)in_sizes; (void)n_in; (void)out_size; (void)ws_size;
    const float* h  = (const float*)d_in[0];
    const float* W  = (const float*)d_in[1];
    const float* aw = (const float*)d_in[2];
    const float* ab = (const float*)d_in[3];
    float* out = (float*)d_out;

    uint16_t* whB = (uint16_t*)d_ws;                       // 16 x 131072 bf16 = 4 MB
    float* s1b    = (float*)((char*)d_ws + (4u << 20));    // 16384 f32
    float* E1g    = s1b + 16384;                           // 16384 f32
    float* E2g    = E1g + 16384;                           // 16384 f32
    float* smaxrg = E2g + 16384;                           // 1024 f32
    uint16_t* whi = (uint16_t*)(smaxrg + 1024);            // 128x128 bf16
    uint16_t* wlo = whi + 16384;                           // 128x128 bf16

    k0_splitW<<<64, 256, 0, stream>>>(W, whi, wlo);
    k1_gemm<<<1024, 256, 0, stream>>>(h, whi, wlo, aw, ab, whB, s1b, E1g, E2g, smaxrg);
    k2_attn<<<2048, 128, 0, stream>>>(whB, s1b, E1g, E2g, smaxrg, out);
}

// Round 3
// 95.282 us; speedup vs baseline: 1.1275x; 1.1275x over previous
//
#include <hip/hip_runtime.h>
#include <hip/hip_bf16.h>
#include <stdint.h>

#define LOG2E 1.4426950408889634f

typedef float f32x4 __attribute__((ext_vector_type(4)));
typedef short s16x8 __attribute__((ext_vector_type(8)));
typedef int   i32x4 __attribute__((ext_vector_type(4)));

__device__ __forceinline__ float bf2f(uint16_t u) {
    uint32_t x = ((uint32_t)u) << 16;
    float f;
    __builtin_memcpy(&f, &x, 4);
    return f;
}
__device__ __forceinline__ uint16_t f2bf(float f) {
    uint32_t x;
    __builtin_memcpy(&x, &f, 4);
    uint32_t r = (x + 0x7fffu + ((x >> 16) & 1u)) >> 16;
    return (uint16_t)r;
}

// -------------------- Kernel 0: split W (fp32) into hi/lo bf16 --------------------
__global__ __launch_bounds__(256) void k0_splitW(
    const float* __restrict__ W, uint16_t* __restrict__ whi, uint16_t* __restrict__ wlo)
{
    int i = blockIdx.x * 256 + threadIdx.x;
    float x = W[i];
    uint16_t hb = f2bf(x);
    whi[i] = hb;
    wlo[i] = f2bf(x - bf2f(hb));
}

// -------------------- Kernel 1: Wh via split-bf16 MFMA; whB frag-order; s1/E1/E2; rowgroup max --
__global__ __launch_bounds__(256) void k1_gemm(
    const float* __restrict__ h, const uint16_t* __restrict__ whi_,
    const uint16_t* __restrict__ wlo_,
    const float* __restrict__ aw, const float* __restrict__ ab,
    uint16_t* __restrict__ whB, float* __restrict__ s1b,
    float* __restrict__ E1g, float* __restrict__ E2g,
    float* __restrict__ smaxrg)
{
    __shared__ float sred[4][16][2];
    const int tid = threadIdx.x;
    const int w = tid >> 6, lane = tid & 63;
    const int q = lane >> 4, n16 = lane & 15;
    const int R0 = blockIdx.x * 16;
    const int f0 = w * 32;

    f32x4 acc[2];
    acc[0] = 0.f; acc[1] = 0.f;

    const float* hrow = h + (size_t)(R0 + n16) * 128 + q * 8;
    const uint16_t* whbase = whi_ + (size_t)(f0 + n16) * 128 + q * 8;
    const uint16_t* wlbase = wlo_ + (size_t)(f0 + n16) * 128 + q * 8;
#pragma unroll
    for (int kc = 0; kc < 4; ++kc) {
        float4 x0 = *(const float4*)(hrow + kc * 32);
        float4 x1 = *(const float4*)(hrow + kc * 32 + 4);
        float xs[8] = {x0.x, x0.y, x0.z, x0.w, x1.x, x1.y, x1.z, x1.w};
        s16x8 ahi, alo;
#pragma unroll
        for (int t = 0; t < 8; ++t) {
            uint16_t hb = f2bf(xs[t]);
            ahi[t] = (short)hb;
            alo[t] = (short)f2bf(xs[t] - bf2f(hb));
        }
#pragma unroll
        for (int fb = 0; fb < 2; ++fb) {
            s16x8 bhi = *(const s16x8*)(whbase + fb * 16 * 128 + kc * 32);
            s16x8 blo = *(const s16x8*)(wlbase + fb * 16 * 128 + kc * 32);
            acc[fb] = __builtin_amdgcn_mfma_f32_16x16x32_bf16(ahi, bhi, acc[fb], 0, 0, 0);
            acc[fb] = __builtin_amdgcn_mfma_f32_16x16x32_bf16(alo, bhi, acc[fb], 0, 0, 0);
            acc[fb] = __builtin_amdgcn_mfma_f32_16x16x32_bf16(ahi, blo, acc[fb], 0, 0, 0);
        }
    }

    float s1p[4] = {0.f, 0.f, 0.f, 0.f}, s2p[4] = {0.f, 0.f, 0.f, 0.f};
#pragma unroll
    for (int fb = 0; fb < 2; ++fb) {
        float a1 = aw[f0 + fb * 16 + n16];
        float a2 = aw[128 + f0 + fb * 16 + n16];
#pragma unroll
        for (int reg = 0; reg < 4; ++reg) {
            s1p[reg] = fmaf(acc[fb][reg], a1, s1p[reg]);
            s2p[reg] = fmaf(acc[fb][reg], a2, s2p[reg]);
        }
    }
#pragma unroll
    for (int off = 1; off < 16; off <<= 1) {
#pragma unroll
        for (int reg = 0; reg < 4; ++reg) {
            s1p[reg] += __shfl_xor(s1p[reg], off);
            s2p[reg] += __shfl_xor(s2p[reg], off);
        }
    }
    if (n16 == 0) {
#pragma unroll
        for (int reg = 0; reg < 4; ++reg) {
            sred[w][q * 4 + reg][0] = s1p[reg];
            sred[w][q * 4 + reg][1] = s2p[reg];
        }
    }
    __syncthreads();
    if (tid < 16) {
        float s1 = sred[0][tid][0] + sred[1][tid][0] + sred[2][tid][0] + sred[3][tid][0];
        float s2 = sred[0][tid][1] + sred[1][tid][1] + sred[2][tid][1] + sred[3][tid][1];
        int R = R0 + tid;
        s1b[R] = LOG2E * (s1 + ab[0]);
        float s2s = LOG2E * s2;
        E1g[R] = __builtin_amdgcn_exp2f(s2s);
        E2g[R] = __builtin_amdgcn_exp2f(0.2f * s2s);
        float m = s2s;
#pragma unroll
        for (int off = 1; off < 16; off <<= 1)
            m = fmaxf(m, __shfl_xor(m, off));
        if (tid == 0) smaxrg[blockIdx.x] = m;
    }

    const int b = R0 >> 10;
    const int jt = (R0 & 1023) >> 5;
    const int rg1 = (R0 >> 4) & 1;
    uint16_t* base = whB + (size_t)b * 131072 + (size_t)jt * 512;
    const int lane8p = (rg1 * 2 + (q >> 1)) * 16 + n16;
#pragma unroll
    for (int fb = 0; fb < 2; ++fb) {
        int fblk = w * 2 + fb;
        uint32_t e0 = f2bf(acc[fb][0]), e1 = f2bf(acc[fb][1]);
        uint32_t e2 = f2bf(acc[fb][2]), e3 = f2bf(acc[fb][3]);
        uint2 val = make_uint2(e0 | (e1 << 16), e2 | (e3 << 16));
        *(uint2*)(base + fblk * 16384 + lane8p * 8 + (q & 1) * 4) = val;
    }
}

// ---- diag-subtraction + epilogue for rowfrag RF (compile-time index -> no scratch) ----
template<int RF>
__device__ __forceinline__ void k2_tail(
    f32x4 (&accrf)[2], f32x4& acclrf,
    int b, int jb, int iw0, int fq, int f0, int q, int n16, float M,
    const uint16_t* __restrict__ whB, const float* __restrict__ s1b,
    const float* __restrict__ E1g, const float* __restrict__ E2g,
    float* __restrict__ out)
{
#pragma unroll
    for (int reg = 0; reg < 4; ++reg) {
        int iw = iw0 + RF * 16 + q * 4 + reg;
        float s1v = s1b[jb + iw];
        float tm = s1v + M;
        float mi = fmaxf(tm, 0.2f * tm);
        float eAr = __builtin_amdgcn_exp2f(s1v - mi);
        float eBr = __builtin_amdgcn_exp2f(fmaf(0.2f, s1v, -mi));
        float p = fmaxf(eAr * E1g[jb + iw], eBr * E2g[jb + iw]);
        float pt = __builtin_bit_cast(float, __builtin_bit_cast(uint32_t, p) & 0xffff0000u);
        acclrf[reg] -= pt;
        int lane_i = ((iw >> 3) & 3) * 16 + n16;
#pragma unroll
        for (int fb = 0; fb < 2; ++fb) {
            size_t a = ((size_t)b << 17) + (size_t)(fq * 2 + fb) * 16384 +
                       (size_t)(iw >> 5) * 512 + lane_i * 8 + (iw & 7);
            float wv_ = bf2f(whB[a]);
            accrf[fb][reg] -= pt * wv_;
        }
    }
#pragma unroll
    for (int reg = 0; reg < 4; ++reg) {
        float rl = 1.0f / acclrf[reg];
        int row = jb + iw0 + RF * 16 + q * 4 + reg;
#pragma unroll
        for (int fb = 0; fb < 2; ++fb) {
            float v = accrf[fb][reg] * rl;
            float e = v > 0.f ? v : (__builtin_amdgcn_exp2f(v * LOG2E) - 1.f);
            out[(size_t)row * 128 + f0 + fb * 16 + n16] = e;
        }
    }
}

// -------------------- Kernel 2: fused attention v6 ---------------------------------------------
// 2048 blocks x 2 waves. Same j-split as v5 BUT all accumulator indexing is compile-time:
// the cross-wave combine and the tail run in wave-uniform branches with literal indices
// (v5's runtime acc[wv]/acc[orf] demoted the accumulators to scratch -> 52 VGPR + disaster).
__global__ __launch_bounds__(128, 4) void k2_attn(
    const uint16_t* __restrict__ whB, const float* __restrict__ s1b,
    const float* __restrict__ E1g, const float* __restrict__ E2g,
    const float* __restrict__ smaxrg, float* __restrict__ out)
{
    __shared__ float red[2][12][64];
    const int tid = threadIdx.x;
    const int wv = tid >> 6;             // wave id: j-half AND tail rowfrag
    const int lane = tid & 63;
    const int q = lane >> 4, n16 = lane & 15;
    const int idx = blockIdx.x;
    const int xcd = idx & 7;
    const int o = idx >> 3;              // [0,256)
    const int b = ((o >> 7) << 3) | xcd; // batches {xcd, xcd+8} stay on one XCD's L2
    const int rem = o & 127;
    const int rg = rem >> 2;             // rowgroup of 32 rows
    const int fq = rem & 3;              // f-quarter (32 f)
    const int jb = b << 10;
    const int iw0 = rg * 32;
    const int f0 = fq * 32;

    // batch max of s2 (plain max; softmax shift-invariance keeps ratio exact)
    float M = smaxrg[(b << 6) | lane];
#pragma unroll
    for (int off = 1; off < 64; off <<= 1)
        M = fmaxf(M, __shfl_xor(M, off));

    // per-lane A-row constants for rowfrags rf=0,1 (rows iw0 + rf*16 + n16), hoisted exps
    float eA[2], eB[2];
#pragma unroll
    for (int rf = 0; rf < 2; ++rf) {
        float s1v = s1b[jb + iw0 + rf * 16 + n16];
        float tm = s1v + M;
        float mi = fmaxf(tm, 0.2f * tm);
        eA[rf] = __builtin_amdgcn_exp2f(s1v - mi);
        eB[rf] = __builtin_amdgcn_exp2f(fmaf(0.2f, s1v, -mi));
    }

    f32x4 acc[2][2], accl[2];
#pragma unroll
    for (int rf = 0; rf < 2; ++rf) {
        acc[rf][0] = 0.f; acc[rf][1] = 0.f; accl[rf] = 0.f;
    }

    s16x8 Bones;
#pragma unroll
    for (int t = 0; t < 8; ++t) Bones[t] = (short)0x3F80;  // bf16(1.0)

    const int fblk0 = fq * 2, fblk1 = fq * 2 + 1;
    const int jt0 = wv << 4;
    const uint16_t* wb = whB + ((size_t)b << 17) + lane * 8;
    const uint16_t* wb0 = wb + jt0 * 512;
    const float* e1q = E1g + jb + jt0 * 32 + q * 8;
    const float* e2q = E2g + jb + jt0 * 32 + q * 8;

    s16x8 Bc0 = *(const s16x8*)(wb0 + fblk0 * 16384);
    s16x8 Bc1 = *(const s16x8*)(wb0 + fblk1 * 16384);
    float4 c1a = *(const float4*)(e1q);
    float4 c1b = *(const float4*)(e1q + 4);
    float4 c2a = *(const float4*)(e2q);
    float4 c2b = *(const float4*)(e2q + 4);

    for (int t = 0; t < 16; ++t) {
        const int tn = (t < 15) ? t + 1 : 15;
        const uint16_t* bpn = wb0 + tn * 512;
        s16x8 Bn0 = *(const s16x8*)(bpn + fblk0 * 16384);
        s16x8 Bn1 = *(const s16x8*)(bpn + fblk1 * 16384);
        float4 n1a = *(const float4*)(e1q + tn * 32);
        float4 n1b = *(const float4*)(e1q + tn * 32 + 4);
        float4 n2a = *(const float4*)(e2q + tn * 32);
        float4 n2b = *(const float4*)(e2q + tn * 32 + 4);

        float e1v[8] = {c1a.x, c1a.y, c1a.z, c1a.w, c1b.x, c1b.y, c1b.z, c1b.w};
        float e2v[8] = {c2a.x, c2a.y, c2a.z, c2a.w, c2b.x, c2b.y, c2b.z, c2b.w};

        s16x8 A[2];
#pragma unroll
        for (int rf = 0; rf < 2; ++rf) {
            i32x4 pk;
#pragma unroll
            for (int pr = 0; pr < 4; ++pr) {
                float p0 = fmaxf(eA[rf] * e1v[2 * pr],     eB[rf] * e2v[2 * pr]);
                float p1 = fmaxf(eA[rf] * e1v[2 * pr + 1], eB[rf] * e2v[2 * pr + 1]);
                // dst = { p1[31:16], p0[31:16] } : truncation pack in one v_perm_b32
                pk[pr] = (int)__builtin_amdgcn_perm(
                    __builtin_bit_cast(uint32_t, p1),
                    __builtin_bit_cast(uint32_t, p0), 0x07060302u);
            }
            A[rf] = __builtin_bit_cast(s16x8, pk);
        }
#pragma unroll
        for (int rf = 0; rf < 2; ++rf) {
            acc[rf][0] = __builtin_amdgcn_mfma_f32_16x16x32_bf16(A[rf], Bc0, acc[rf][0], 0, 0, 0);
            acc[rf][1] = __builtin_amdgcn_mfma_f32_16x16x32_bf16(A[rf], Bc1, acc[rf][1], 0, 0, 0);
            accl[rf]   = __builtin_amdgcn_mfma_f32_16x16x32_bf16(A[rf], Bones, accl[rf], 0, 0, 0);
        }
        Bc0 = Bn0; Bc1 = Bn1;
        c1a = n1a; c1b = n1b; c2a = n2a; c2b = n2b;
    }

    // cross-wave combine: wave 0 exports rowfrag 1, wave 1 exports rowfrag 0.
    // All indices literal inside wave-uniform branches; barrier outside (reached once by all).
    if (wv == 0) {
#pragma unroll
        for (int fb = 0; fb < 2; ++fb)
#pragma unroll
            for (int reg = 0; reg < 4; ++reg)
                red[0][fb * 4 + reg][lane] = acc[1][fb][reg];
#pragma unroll
        for (int reg = 0; reg < 4; ++reg)
            red[0][8 + reg][lane] = accl[1][reg];
    } else {
#pragma unroll
        for (int fb = 0; fb < 2; ++fb)
#pragma unroll
            for (int reg = 0; reg < 4; ++reg)
                red[1][fb * 4 + reg][lane] = acc[0][fb][reg];
#pragma unroll
        for (int reg = 0; reg < 4; ++reg)
            red[1][8 + reg][lane] = accl[0][reg];
    }
    __syncthreads();
    if (wv == 0) {
#pragma unroll
        for (int fb = 0; fb < 2; ++fb)
#pragma unroll
            for (int reg = 0; reg < 4; ++reg)
                acc[0][fb][reg] += red[1][fb * 4 + reg][lane];
#pragma unroll
        for (int reg = 0; reg < 4; ++reg)
            accl[0][reg] += red[1][8 + reg][lane];
        k2_tail<0>(acc[0], accl[0], b, jb, iw0, fq, f0, q, n16, M,
                   whB, s1b, E1g, E2g, out);
    } else {
#pragma unroll
        for (int fb = 0; fb < 2; ++fb)
#pragma unroll
            for (int reg = 0; reg < 4; ++reg)
                acc[1][fb][reg] += red[0][fb * 4 + reg][lane];
#pragma unroll
        for (int reg = 0; reg < 4; ++reg)
            accl[1][reg] += red[0][8 + reg][lane];
        k2_tail<1>(acc[1], accl[1], b, jb, iw0, fq, f0, q, n16, M,
                   whB, s1b, E1g, E2g, out);
    }
}

extern "C" void kernel_launch(void* const* d_in, const int* in_sizes, int n_in,
                              void* d_out, int out_size, void* d_ws, size_t ws_size,
                              hipStream_t stream) {
    (void)in_sizes; (void)n_in; (void)out_size; (void)ws_size;
    const float* h  = (const float*)d_in[0];
    const float* W  = (const float*)d_in[1];
    const float* aw = (const float*)d_in[2];
    const float* ab = (const float*)d_in[3];
    float* out = (float*)d_out;

    uint16_t* whB = (uint16_t*)d_ws;                       // 16 x 131072 bf16 = 4 MB
    float* s1b    = (float*)((char*)d_ws + (4u << 20));    // 16384 f32
    float* E1g    = s1b + 16384;                           // 16384 f32
    float* E2g    = E1g + 16384;                           // 16384 f32
    float* smaxrg = E2g + 16384;                           // 1024 f32
    uint16_t* whi = (uint16_t*)(smaxrg + 1024);            // 128x128 bf16
    uint16_t* wlo = whi + 16384;                           // 128x128 bf16

    k0_splitW<<<64, 256, 0, stream>>>(W, whi, wlo);
    k1_gemm<<<1024, 256, 0, stream>>>(h, whi, wlo, aw, ab, whB, s1b, E1g, E2g, smaxrg);
    k2_attn<<<2048, 128, 0, stream>>>(whB, s1b, E1g, E2g, smaxrg, out);
}

// Round 4
// 92.745 us; speedup vs baseline: 1.1584x; 1.0274x over previous
//
#include <hip/hip_runtime.h>
#include <hip/hip_bf16.h>
#include <stdint.h>

#define LOG2E 1.4426950408889634f

typedef float f32x4 __attribute__((ext_vector_type(4)));
typedef float f32x2 __attribute__((ext_vector_type(2)));
typedef short s16x8 __attribute__((ext_vector_type(8)));
typedef int   i32x4 __attribute__((ext_vector_type(4)));

__device__ __forceinline__ float bf2f(uint16_t u) {
    uint32_t x = ((uint32_t)u) << 16;
    float f;
    __builtin_memcpy(&f, &x, 4);
    return f;
}
__device__ __forceinline__ uint16_t f2bf(float f) {
    uint32_t x;
    __builtin_memcpy(&x, &f, 4);
    uint32_t r = (x + 0x7fffu + ((x >> 16) & 1u)) >> 16;
    return (uint16_t)r;
}

// -------------------- Kernel 0: split W (fp32) into hi/lo bf16 --------------------
__global__ __launch_bounds__(256) void k0_splitW(
    const float* __restrict__ W, uint16_t* __restrict__ whi, uint16_t* __restrict__ wlo)
{
    int i = blockIdx.x * 256 + threadIdx.x;
    float x = W[i];
    uint16_t hb = f2bf(x);
    whi[i] = hb;
    wlo[i] = f2bf(x - bf2f(hb));
}

// -------------------- Kernel 1: Wh via split-bf16 MFMA; whB frag-order; s1/E1/E2; rowgroup max --
// v2: the h-tile (16 rows x 128) is split into hi/lo bf16 ONCE per block (cooperatively, into
// LDS in MFMA-fragment order) instead of redundantly by each of the 4 waves. Producer mapping
// is chosen so LDS write addr == tid*16 (lane-contiguous b128, conflict-free) and consumer read
// addr == (kc*64+lane)*16 (lane-contiguous, conflict-free). Split arithmetic is bit-identical.
__global__ __launch_bounds__(256) void k1_gemm(
    const float* __restrict__ h, const uint16_t* __restrict__ whi_,
    const uint16_t* __restrict__ wlo_,
    const float* __restrict__ aw, const float* __restrict__ ab,
    uint16_t* __restrict__ whB, float* __restrict__ s1b,
    float* __restrict__ E1g, float* __restrict__ E2g,
    float* __restrict__ smaxrg)
{
    __shared__ uint16_t ahi_s[256 * 8];   // slot = kc*64 + q*16 + r == tid
    __shared__ uint16_t alo_s[256 * 8];
    __shared__ float sred[4][16][2];
    const int tid = threadIdx.x;
    const int w = tid >> 6, lane = tid & 63;
    const int q = lane >> 4, n16 = lane & 15;
    const int R0 = blockIdx.x * 16;
    const int f0 = w * 32;

    // ---- cooperative h split: thread tid owns slot tid = (kc, q, r) ----
    {
        const int r  = tid & 15;
        const int qq = (tid >> 4) & 3;
        const int kc = tid >> 6;
        const float* hp = h + (size_t)(R0 + r) * 128 + kc * 32 + qq * 8;
        float4 x0 = *(const float4*)(hp);
        float4 x1 = *(const float4*)(hp + 4);
        float xs[8] = {x0.x, x0.y, x0.z, x0.w, x1.x, x1.y, x1.z, x1.w};
        s16x8 hi8, lo8;
#pragma unroll
        for (int t = 0; t < 8; ++t) {
            uint16_t hb = f2bf(xs[t]);
            hi8[t] = (short)hb;
            lo8[t] = (short)f2bf(xs[t] - bf2f(hb));
        }
        *(s16x8*)(ahi_s + tid * 8) = hi8;
        *(s16x8*)(alo_s + tid * 8) = lo8;
    }
    __syncthreads();

    f32x4 acc[2];
    acc[0] = 0.f; acc[1] = 0.f;

    const uint16_t* whbase = whi_ + (size_t)(f0 + n16) * 128 + q * 8;
    const uint16_t* wlbase = wlo_ + (size_t)(f0 + n16) * 128 + q * 8;
#pragma unroll
    for (int kc = 0; kc < 4; ++kc) {
        s16x8 ahi = *(const s16x8*)(ahi_s + (kc * 64 + lane) * 8);
        s16x8 alo = *(const s16x8*)(alo_s + (kc * 64 + lane) * 8);
#pragma unroll
        for (int fb = 0; fb < 2; ++fb) {
            s16x8 bhi = *(const s16x8*)(whbase + fb * 16 * 128 + kc * 32);
            s16x8 blo = *(const s16x8*)(wlbase + fb * 16 * 128 + kc * 32);
            acc[fb] = __builtin_amdgcn_mfma_f32_16x16x32_bf16(ahi, bhi, acc[fb], 0, 0, 0);
            acc[fb] = __builtin_amdgcn_mfma_f32_16x16x32_bf16(alo, bhi, acc[fb], 0, 0, 0);
            acc[fb] = __builtin_amdgcn_mfma_f32_16x16x32_bf16(ahi, blo, acc[fb], 0, 0, 0);
        }
    }

    float s1p[4] = {0.f, 0.f, 0.f, 0.f}, s2p[4] = {0.f, 0.f, 0.f, 0.f};
#pragma unroll
    for (int fb = 0; fb < 2; ++fb) {
        float a1 = aw[f0 + fb * 16 + n16];
        float a2 = aw[128 + f0 + fb * 16 + n16];
#pragma unroll
        for (int reg = 0; reg < 4; ++reg) {
            s1p[reg] = fmaf(acc[fb][reg], a1, s1p[reg]);
            s2p[reg] = fmaf(acc[fb][reg], a2, s2p[reg]);
        }
    }
#pragma unroll
    for (int off = 1; off < 16; off <<= 1) {
#pragma unroll
        for (int reg = 0; reg < 4; ++reg) {
            s1p[reg] += __shfl_xor(s1p[reg], off);
            s2p[reg] += __shfl_xor(s2p[reg], off);
        }
    }
    if (n16 == 0) {
#pragma unroll
        for (int reg = 0; reg < 4; ++reg) {
            sred[w][q * 4 + reg][0] = s1p[reg];
            sred[w][q * 4 + reg][1] = s2p[reg];
        }
    }
    __syncthreads();
    if (tid < 16) {
        float s1 = sred[0][tid][0] + sred[1][tid][0] + sred[2][tid][0] + sred[3][tid][0];
        float s2 = sred[0][tid][1] + sred[1][tid][1] + sred[2][tid][1] + sred[3][tid][1];
        int R = R0 + tid;
        s1b[R] = LOG2E * (s1 + ab[0]);
        float s2s = LOG2E * s2;
        E1g[R] = __builtin_amdgcn_exp2f(s2s);
        E2g[R] = __builtin_amdgcn_exp2f(0.2f * s2s);
        float m = s2s;
#pragma unroll
        for (int off = 1; off < 16; off <<= 1)
            m = fmaxf(m, __shfl_xor(m, off));
        if (tid == 0) smaxrg[blockIdx.x] = m;
    }

    const int b = R0 >> 10;
    const int jt = (R0 & 1023) >> 5;
    const int rg1 = (R0 >> 4) & 1;
    uint16_t* base = whB + (size_t)b * 131072 + (size_t)jt * 512;
    const int lane8p = (rg1 * 2 + (q >> 1)) * 16 + n16;
#pragma unroll
    for (int fb = 0; fb < 2; ++fb) {
        int fblk = w * 2 + fb;
        uint32_t e0 = f2bf(acc[fb][0]), e1 = f2bf(acc[fb][1]);
        uint32_t e2 = f2bf(acc[fb][2]), e3 = f2bf(acc[fb][3]);
        uint2 val = make_uint2(e0 | (e1 << 16), e2 | (e3 << 16));
        *(uint2*)(base + fblk * 16384 + lane8p * 8 + (q & 1) * 4) = val;
    }
}

// ---- diag-subtraction + epilogue for rowfrag RF (compile-time index -> no scratch) ----
template<int RF>
__device__ __forceinline__ void k2_tail(
    f32x4 (&accrf)[2], f32x4& acclrf,
    int b, int jb, int iw0, int fq, int f0, int q, int n16, float M,
    const uint16_t* __restrict__ whB, const float* __restrict__ s1b,
    const float* __restrict__ E1g, const float* __restrict__ E2g,
    float* __restrict__ out)
{
#pragma unroll
    for (int reg = 0; reg < 4; ++reg) {
        int iw = iw0 + RF * 16 + q * 4 + reg;
        float s1v = s1b[jb + iw];
        float tm = s1v + M;
        float mi = fmaxf(tm, 0.2f * tm);
        float eAr = __builtin_amdgcn_exp2f(s1v - mi);
        float eBr = __builtin_amdgcn_exp2f(fmaf(0.2f, s1v, -mi));
        float p = fmaxf(eAr * E1g[jb + iw], eBr * E2g[jb + iw]);
        float pt = __builtin_bit_cast(float, __builtin_bit_cast(uint32_t, p) & 0xffff0000u);
        acclrf[reg] -= pt;
        int lane_i = ((iw >> 3) & 3) * 16 + n16;
#pragma unroll
        for (int fb = 0; fb < 2; ++fb) {
            size_t a = ((size_t)b << 17) + (size_t)(fq * 2 + fb) * 16384 +
                       (size_t)(iw >> 5) * 512 + lane_i * 8 + (iw & 7);
            float wv_ = bf2f(whB[a]);
            accrf[fb][reg] -= pt * wv_;
        }
    }
#pragma unroll
    for (int reg = 0; reg < 4; ++reg) {
        float rl = 1.0f / acclrf[reg];
        int row = jb + iw0 + RF * 16 + q * 4 + reg;
#pragma unroll
        for (int fb = 0; fb < 2; ++fb) {
            float v = accrf[fb][reg] * rl;
            float e = v > 0.f ? v : (__builtin_amdgcn_exp2f(v * LOG2E) - 1.f);
            out[(size_t)row * 128 + f0 + fb * 16 + n16] = e;
        }
    }
}

// -------------------- Kernel 2: fused attention v7 ---------------------------------------------
// Same structure as v6 (2048 blocks x 2 waves, compile-time acc indexing). P-gen products are
// written as float2 ext-vector ops so the backend can form v_pk_mul_f32 (gfx90a+ packed fp32) —
// 16 muls -> 8 pk_muls per iter; fmax stays scalar (no packed f32 max). Bit-identical fp32 math.
__global__ __launch_bounds__(128, 4) void k2_attn(
    const uint16_t* __restrict__ whB, const float* __restrict__ s1b,
    const float* __restrict__ E1g, const float* __restrict__ E2g,
    const float* __restrict__ smaxrg, float* __restrict__ out)
{
    __shared__ float red[2][12][64];
    const int tid = threadIdx.x;
    const int wv = tid >> 6;             // wave id: j-half AND tail rowfrag
    const int lane = tid & 63;
    const int q = lane >> 4, n16 = lane & 15;
    const int idx = blockIdx.x;
    const int xcd = idx & 7;
    const int o = idx >> 3;              // [0,256)
    const int b = ((o >> 7) << 3) | xcd; // batches {xcd, xcd+8} stay on one XCD's L2
    const int rem = o & 127;
    const int rg = rem >> 2;             // rowgroup of 32 rows
    const int fq = rem & 3;              // f-quarter (32 f)
    const int jb = b << 10;
    const int iw0 = rg * 32;
    const int f0 = fq * 32;

    // batch max of s2 (plain max; softmax shift-invariance keeps ratio exact)
    float M = smaxrg[(b << 6) | lane];
#pragma unroll
    for (int off = 1; off < 64; off <<= 1)
        M = fmaxf(M, __shfl_xor(M, off));

    // per-lane A-row constants for rowfrags rf=0,1 (rows iw0 + rf*16 + n16), hoisted exps
    f32x2 eA2[2], eB2[2];
#pragma unroll
    for (int rf = 0; rf < 2; ++rf) {
        float s1v = s1b[jb + iw0 + rf * 16 + n16];
        float tm = s1v + M;
        float mi = fmaxf(tm, 0.2f * tm);
        float ea = __builtin_amdgcn_exp2f(s1v - mi);
        float eb = __builtin_amdgcn_exp2f(fmaf(0.2f, s1v, -mi));
        eA2[rf][0] = ea; eA2[rf][1] = ea;
        eB2[rf][0] = eb; eB2[rf][1] = eb;
    }

    f32x4 acc[2][2], accl[2];
#pragma unroll
    for (int rf = 0; rf < 2; ++rf) {
        acc[rf][0] = 0.f; acc[rf][1] = 0.f; accl[rf] = 0.f;
    }

    s16x8 Bones;
#pragma unroll
    for (int t = 0; t < 8; ++t) Bones[t] = (short)0x3F80;  // bf16(1.0)

    const int fblk0 = fq * 2, fblk1 = fq * 2 + 1;
    const int jt0 = wv << 4;
    const uint16_t* wb = whB + ((size_t)b << 17) + lane * 8;
    const uint16_t* wb0 = wb + jt0 * 512;
    const float* e1q = E1g + jb + jt0 * 32 + q * 8;
    const float* e2q = E2g + jb + jt0 * 32 + q * 8;

    s16x8 Bc0 = *(const s16x8*)(wb0 + fblk0 * 16384);
    s16x8 Bc1 = *(const s16x8*)(wb0 + fblk1 * 16384);
    float4 c1a = *(const float4*)(e1q);
    float4 c1b = *(const float4*)(e1q + 4);
    float4 c2a = *(const float4*)(e2q);
    float4 c2b = *(const float4*)(e2q + 4);

    for (int t = 0; t < 16; ++t) {
        const int tn = (t < 15) ? t + 1 : 15;
        const uint16_t* bpn = wb0 + tn * 512;
        s16x8 Bn0 = *(const s16x8*)(bpn + fblk0 * 16384);
        s16x8 Bn1 = *(const s16x8*)(bpn + fblk1 * 16384);
        float4 n1a = *(const float4*)(e1q + tn * 32);
        float4 n1b = *(const float4*)(e1q + tn * 32 + 4);
        float4 n2a = *(const float4*)(e2q + tn * 32);
        float4 n2b = *(const float4*)(e2q + tn * 32 + 4);

        float e1v[8] = {c1a.x, c1a.y, c1a.z, c1a.w, c1b.x, c1b.y, c1b.z, c1b.w};
        float e2v[8] = {c2a.x, c2a.y, c2a.z, c2a.w, c2b.x, c2b.y, c2b.z, c2b.w};

        s16x8 A[2];
#pragma unroll
        for (int rf = 0; rf < 2; ++rf) {
            i32x4 pk;
#pragma unroll
            for (int pr = 0; pr < 4; ++pr) {
                f32x2 e1p; e1p[0] = e1v[2 * pr]; e1p[1] = e1v[2 * pr + 1];
                f32x2 e2p; e2p[0] = e2v[2 * pr]; e2p[1] = e2v[2 * pr + 1];
                f32x2 m1 = eA2[rf] * e1p;   // v_pk_mul_f32 candidate
                f32x2 m2 = eB2[rf] * e2p;   // v_pk_mul_f32 candidate
                float p0 = fmaxf(m1[0], m2[0]);
                float p1 = fmaxf(m1[1], m2[1]);
                // dst = { p1[31:16], p0[31:16] } : truncation pack in one v_perm_b32
                pk[pr] = (int)__builtin_amdgcn_perm(
                    __builtin_bit_cast(uint32_t, p1),
                    __builtin_bit_cast(uint32_t, p0), 0x07060302u);
            }
            A[rf] = __builtin_bit_cast(s16x8, pk);
        }
#pragma unroll
        for (int rf = 0; rf < 2; ++rf) {
            acc[rf][0] = __builtin_amdgcn_mfma_f32_16x16x32_bf16(A[rf], Bc0, acc[rf][0], 0, 0, 0);
            acc[rf][1] = __builtin_amdgcn_mfma_f32_16x16x32_bf16(A[rf], Bc1, acc[rf][1], 0, 0, 0);
            accl[rf]   = __builtin_amdgcn_mfma_f32_16x16x32_bf16(A[rf], Bones, accl[rf], 0, 0, 0);
        }
        Bc0 = Bn0; Bc1 = Bn1;
        c1a = n1a; c1b = n1b; c2a = n2a; c2b = n2b;
    }

    // cross-wave combine: wave 0 exports rowfrag 1, wave 1 exports rowfrag 0.
    // All indices literal inside wave-uniform branches; barrier outside (reached once by all).
    if (wv == 0) {
#pragma unroll
        for (int fb = 0; fb < 2; ++fb)
#pragma unroll
            for (int reg = 0; reg < 4; ++reg)
                red[0][fb * 4 + reg][lane] = acc[1][fb][reg];
#pragma unroll
        for (int reg = 0; reg < 4; ++reg)
            red[0][8 + reg][lane] = accl[1][reg];
    } else {
#pragma unroll
        for (int fb = 0; fb < 2; ++fb)
#pragma unroll
            for (int reg = 0; reg < 4; ++reg)
                red[1][fb * 4 + reg][lane] = acc[0][fb][reg];
#pragma unroll
        for (int reg = 0; reg < 4; ++reg)
            red[1][8 + reg][lane] = accl[0][reg];
    }
    __syncthreads();
    {
        float M_ = M;
        if (wv == 0) {
#pragma unroll
            for (int fb = 0; fb < 2; ++fb)
#pragma unroll
                for (int reg = 0; reg < 4; ++reg)
                    acc[0][fb][reg] += red[1][fb * 4 + reg][lane];
#pragma unroll
            for (int reg = 0; reg < 4; ++reg)
                accl[0][reg] += red[1][8 + reg][lane];
            k2_tail<0>(acc[0], accl[0], b, jb, iw0, fq, f0, q, n16, M_,
                       whB, s1b, E1g, E2g, out);
        } else {
#pragma unroll
            for (int fb = 0; fb < 2; ++fb)
#pragma unroll
                for (int reg = 0; reg < 4; ++reg)
                    acc[1][fb][reg] += red[0][fb * 4 + reg][lane];
#pragma unroll
            for (int reg = 0; reg < 4; ++reg)
                accl[1][reg] += red[0][8 + reg][lane];
            k2_tail<1>(acc[1], accl[1], b, jb, iw0, fq, f0, q, n16, M_,
                       whB, s1b, E1g, E2g, out);
        }
    }
}

extern "C" void kernel_launch(void* const* d_in, const int* in_sizes, int n_in,
                              void* d_out, int out_size, void* d_ws, size_t ws_size,
                              hipStream_t stream) {
    (void)in_sizes; (void)n_in; (void)out_size; (void)ws_size;
    const float* h  = (const float*)d_in[0];
    const float* W  = (const float*)d_in[1];
    const float* aw = (const float*)d_in[2];
    const float* ab = (const float*)d_in[3];
    float* out = (float*)d_out;

    uint16_t* whB = (uint16_t*)d_ws;                       // 16 x 131072 bf16 = 4 MB
    float* s1b    = (float*)((char*)d_ws + (4u << 20));    // 16384 f32
    float* E1g    = s1b + 16384;                           // 16384 f32
    float* E2g    = E1g + 16384;                           // 16384 f32
    float* smaxrg = E2g + 16384;                           // 1024 f32
    uint16_t* whi = (uint16_t*)(smaxrg + 1024);            // 128x128 bf16
    uint16_t* wlo = whi + 16384;                           // 128x128 bf16

    k0_splitW<<<64, 256, 0, stream>>>(W, whi, wlo);
    k1_gemm<<<1024, 256, 0, stream>>>(h, whi, wlo, aw, ab, whB, s1b, E1g, E2g, smaxrg);
    k2_attn<<<2048, 128, 0, stream>>>(whB, s1b, E1g, E2g, smaxrg, out);
}